// Round 1
// baseline (48.243 us; speedup 1.0000x reference)
//
#include <hip/hip_runtime.h>

// Locally-connected 2D conv, fp32.
// x:(8,32,64,64)  weights:(64,64,32,32,3,3)  bias:(32)  out:(8,32,64,64)
// out[b,o,i,j] = bias[o] + sum_{c,d4,d5} x[b,c,i+d5-1,j+d4-1] * W[i,j,o,c,d4,d5]
// (weight kernel dims are spatially transposed vs the patch, per the einsum
//  'bchwij,ijocwh->boij')

#define NB 8
#define NC 32
#define NO 32
#define NH 64
#define NW 64
#define KK 288   // NC*3*3

__global__ __launch_bounds__(256) void lc2d_kernel(
    const float* __restrict__ x, const float* __restrict__ w,
    const float* __restrict__ bias, float* __restrict__ out) {
  const int loc = blockIdx.x;          // location index i*64 + j
  const int i = loc >> 6;
  const int j = loc & 63;
  const int t = threadIdx.x;

  __shared__ float xs[NB * KK];        // 9216 B

  // Stage x patch: xs[b*288 + c*9 + a*3 + bb] = x[b,c,i+bb-1,j+a-1] (zero-pad)
  // 2304 elements, 9 per thread.
#pragma unroll
  for (int r = 0; r < 9; ++r) {
    int e = t + r * 256;
    int b = e / KK;
    int k = e - b * KK;
    int c = k / 9;
    int r9 = k - c * 9;
    int a = r9 / 3;                    // col offset (W axis)
    int bb = r9 - a * 3;               // row offset (H axis)
    int y = i + bb - 1;
    int xc = j + a - 1;
    float v = 0.f;
    if ((unsigned)y < 64u && (unsigned)xc < 64u)
      v = x[((b * NC + c) * NH + y) * NW + xc];
    xs[e] = v;
  }

  // Thread (o, kc) owns weight k-range [kc*36, kc*36+36) of output channel o.
  const int o = t >> 3;
  const int kc = t & 7;
  const float4* wp = reinterpret_cast<const float4*>(
      w + ((size_t)loc * NO + o) * KK + kc * 36);
  float4 wf[9];
#pragma unroll
  for (int s = 0; s < 9; ++s) wf[s] = wp[s];

  __syncthreads();

  const float4* xs4 = reinterpret_cast<const float4*>(xs);
  float acc[NB];
#pragma unroll
  for (int b = 0; b < NB; ++b) acc[b] = 0.f;

#pragma unroll
  for (int b = 0; b < NB; ++b) {
#pragma unroll
    for (int s = 0; s < 9; ++s) {
      float4 xv = xs4[b * 72 + kc * 9 + s];
      float4 wv = wf[s];
      acc[b] = fmaf(wv.x, xv.x, acc[b]);
      acc[b] = fmaf(wv.y, xv.y, acc[b]);
      acc[b] = fmaf(wv.z, xv.z, acc[b]);
      acc[b] = fmaf(wv.w, xv.w, acc[b]);
    }
  }

  // Butterfly reduce-scatter across the 8 kc-lanes of each o-group:
  // lane (o,kc) ends with the full K-sum for batch b == kc.
  float p8[8];
#pragma unroll
  for (int b = 0; b < 8; ++b) p8[b] = __shfl_xor(acc[b], 4);
  float c4[4];
#pragma unroll
  for (int b = 0; b < 4; ++b)
    c4[b] = (kc & 4) ? (acc[b + 4] + p8[b + 4]) : (acc[b] + p8[b]);
  float p4[4];
#pragma unroll
  for (int b = 0; b < 4; ++b) p4[b] = __shfl_xor(c4[b], 2);
  float c2[2];
#pragma unroll
  for (int b = 0; b < 2; ++b)
    c2[b] = (kc & 2) ? (c4[b + 2] + p4[b + 2]) : (c4[b] + p4[b]);
  float p2[2];
#pragma unroll
  for (int b = 0; b < 2; ++b) p2[b] = __shfl_xor(c2[b], 1);
  float tot = (kc & 1) ? (c2[1] + p2[1]) : (c2[0] + p2[0]);

  out[((kc * NO + o) * NH + i) * NW + j] = tot + bias[o];
}

extern "C" void kernel_launch(void* const* d_in, const int* in_sizes, int n_in,
                              void* d_out, int out_size, void* d_ws, size_t ws_size,
                              hipStream_t stream) {
  const float* x    = (const float*)d_in[0];
  const float* w    = (const float*)d_in[1];
  const float* bias = (const float*)d_in[2];
  float* out = (float*)d_out;
  lc2d_kernel<<<dim3(NH * NW), dim3(256), 0, stream>>>(x, w, bias, out);
}